// Round 15
// baseline (437.501 us; speedup 1.0000x reference)
//
#include <hip/hip_runtime.h>
#include <hip/hip_bf16.h>

#define HID 128
#define NNODES 50000
#define NEDGES 800000
#define NGRAPHS 64
#define BN_EPS 1e-5f
#define CAP 64  // bucket capacity; deg ~ Poisson(16), P(deg>63) ~ 1e-21

typedef __attribute__((ext_vector_type(8))) short short8;   // 8 bf16 (4 VGPRs)
typedef __attribute__((ext_vector_type(4))) float f32x4;    // MFMA acc

static __device__ __forceinline__ unsigned short f2bf(float v) {
  __hip_bfloat16 b = __float2bfloat16(v);  // round-to-nearest
  return *reinterpret_cast<unsigned short*>(&b);
}
static __device__ __forceinline__ float bf2f(unsigned short u) {
  return __uint_as_float(((unsigned)u) << 16);
}

// split fp32 -> hi+lo bf16 pair (bf16x3 scheme), 8 contiguous LDS floats
static __device__ __forceinline__ void split8(const float* __restrict__ p,
                                              short8& hi, short8& lo) {
  #pragma unroll
  for (int j = 0; j < 8; j++) {
    float v = p[j];
    unsigned short h = f2bf(v);
    hi[j] = (short)h;
    lo[j] = (short)f2bf(v - bf2f(h));
  }
}

// ===========================================================================
// prep (single kernel): xbf = bf16(node_emb[x_idx]) + bucket-CSR build +
// weight pack (MFMA B-frag layout, hi/lo split).  [round-10 proven]
// ===========================================================================
__global__ __launch_bounds__(256) void prep_kernel(
    const int* __restrict__ x_idx, const float* __restrict__ node_emb,
    unsigned int* __restrict__ xb2, const int* __restrict__ eidx,
    const int* __restrict__ eattr, int* __restrict__ cnt,
    int* __restrict__ eout, const float* __restrict__ W1,
    const float* __restrict__ W2, unsigned short* __restrict__ Wpk) {
  int i = blockIdx.x * 256 + threadIdx.x;
  int stride = gridDim.x * 256;
  const float2* ne2 = (const float2*)node_emb;
  for (int t = i; t < NNODES * (HID / 2); t += stride) {
    int n = t >> 6;  // HID/2 == 64
    int c2 = t & 63;
    float2 v = ne2[x_idx[n] * 64 + c2];
    xb2[t] = (unsigned)f2bf(v.x) | ((unsigned)f2bf(v.y) << 16);
  }
  for (int e = i; e < NEDGES; e += stride) {
    int d = eidx[NEDGES + e];
    int pos = atomicAdd(&cnt[d], 1);
    if (pos < CAP) eout[((size_t)d << 6) + pos] = eidx[e] | (eattr[e] << 16);
  }
  for (int idx = i; idx < 65536; idx += stride) {
    int j = idx & 7;
    int l = (idx >> 3) & 63;
    int q = (idx >> 9) & 3;
    int t = (idx >> 11) & 7;
    int m = idx >> 14;
    int k = ((l >> 4) << 3) + j + (q << 5);
    int n = (t << 4) + (l & 15);
    int layer = m >> 1;
    const float* W = (m & 1) ? W2 : W1;
    float w = W[(size_t)layer * HID * HID + k * HID + n];
    unsigned short h = f2bf(w);
    Wpk[idx] = h;
    Wpk[idx + 65536] = f2bf(w - bf2f(h));
  }
}

// ===========================================================================
// Fused GINE layer [round-10 gather/GEMM], NT=50 so grid = 1000 <= 1024
// resident capacity (4 blocks/CU x 8 waves) -> ONE dispatch round (round 10's
// 1563-block grid needed 2, second 53% empty). hA padded to 64 rows; pad rows
// zeroed and never read back (GEMM rows are independent).
// Gather: wave w owns rows {w, w+8, ...}; lanes = 16 ch-octets x 4 edge
// slots (16B/lane bf16 rows). GEMM: wave w -> 16-ch tile w x 4 row-tiles,
// mfma 16x16x32_bf16, bf16x3 hi/lo split (fp32-grade).
// ===========================================================================
#define NT 50
#define ROWS 64
#define LDAF 132  // 128+4 floats: float4-aligned rows
#define GRID_GINE (NNODES / NT)  // 1000 exact

__global__ __launch_bounds__(512, 8) void gine_mlp_kernel(
    const unsigned short* __restrict__ in_bf,
    const float* __restrict__ instats,
    const float* __restrict__ gam, const float* __restrict__ bet,
    const int* __restrict__ cnt, const int* __restrict__ eout,
    const float* __restrict__ edge_emb,
    const short8* __restrict__ Wh, const short8* __restrict__ Wl,
    const float* __restrict__ b1, const float* __restrict__ b2,
    unsigned short* __restrict__ out_bf, float* __restrict__ stats,
    const int* __restrict__ batch, float* __restrict__ gpool) {
  __shared__ __align__(16) float hA[ROWS * LDAF];  // h0 -> h1 -> h2 (reused)
  __shared__ __align__(16) float sheL[4 * HID];    // sh[c] + edge_emb[a][c]

  const int tid = threadIdx.x;
  const int lane = tid & 63;
  const int wave = tid >> 6;   // 0..7
  const int base = blockIdx.x * NT;

  // ---- she table (BN shift of previous layer folded into edge emb) ----
  {
    int c = tid & 127;
    float shc = 0.0f;
    if (instats) {
      float mu = instats[c] * (1.0f / NNODES);
      float var = instats[HID + c] * (1.0f / NNODES) - mu * mu;
      float s = gam[c] * rsqrtf(var + BN_EPS);
      shc = bet[c] - mu * s;
    }
    sheL[tid] = shc + edge_emb[tid];  // tid < 512 == 4*HID
  }

  // ---- per-lane affine over 8 channels (c8*8 .. c8*8+7) ----
  const int c8 = lane & 15;
  const int grp = lane >> 4;
  float scl8[8], sh8[8];
  #pragma unroll
  for (int j = 0; j < 8; j++) { scl8[j] = 1.0f; sh8[j] = 0.0f; }
  if (instats) {
    #pragma unroll
    for (int j = 0; j < 8; j++) {
      int c = c8 * 8 + j;
      float mu = instats[c] * (1.0f / NNODES);
      float var = instats[HID + c] * (1.0f / NNODES) - mu * mu;
      float s = gam[c] * rsqrtf(var + BN_EPS);
      scl8[j] = s;
      sh8[j] = bet[c] - mu * s;
    }
  }
  __syncthreads();  // sheL ready

  // ---- phase 1: gather (wave w -> rows {w, w+8, ..., w+56}) ----
  {
    const short8* in8 = (const short8*)in_bf;  // row = 16 short8s
    int degs[8];
    #pragma unroll
    for (int i = 0; i < 8; i++) {  // prefetch degrees (independent loads)
      int n = wave + 8 * i;
      degs[i] = (n < NT) ? min(cnt[base + n], CAP) : 0;
    }
    for (int i = 0; i < 8; i++) {
      int n = wave + 8 * i;
      float acc[8];
      #pragma unroll
      for (int j = 0; j < 8; j++) acc[j] = 0.0f;
      if (n < NT) {
        int node = base + n;
        int deg = degs[i];
        const int* ep = eout + ((size_t)node << 6);
        if (grp == 0) {
          short8 s = in8[node * 16 + c8];
          #pragma unroll
          for (int j = 0; j < 8; j++)
            acc[j] = fmaf(bf2f((unsigned short)s[j]), scl8[j], sh8[j]);
        }
        int e = 0;
        for (; e + 8 <= deg; e += 8) {  // 8 edges: 2 per slot
          int pA = ep[e + grp];
          int pB = ep[e + 4 + grp];
          short8 xA = in8[(pA & 0xFFFF) * 16 + c8];
          short8 xB = in8[(pB & 0xFFFF) * 16 + c8];
          const float4* sA = (const float4*)&sheL[((pA >> 16) << 7) + c8 * 8];
          const float4* sB = (const float4*)&sheL[((pB >> 16) << 7) + c8 * 8];
          float4 sA0 = sA[0], sA1 = sA[1], sB0 = sB[0], sB1 = sB[1];
          #pragma unroll
          for (int j = 0; j < 8; j++) {
            float seA = (j < 4) ? ((const float*)&sA0)[j] : ((const float*)&sA1)[j - 4];
            float seB = (j < 4) ? ((const float*)&sB0)[j] : ((const float*)&sB1)[j - 4];
            acc[j] += fmaxf(fmaf(bf2f((unsigned short)xA[j]), scl8[j], seA), 0.0f) +
                      fmaxf(fmaf(bf2f((unsigned short)xB[j]), scl8[j], seB), 0.0f);
          }
        }
        if (e + 4 <= deg) {
          int pA = ep[e + grp];
          short8 xA = in8[(pA & 0xFFFF) * 16 + c8];
          const float4* sA = (const float4*)&sheL[((pA >> 16) << 7) + c8 * 8];
          float4 sA0 = sA[0], sA1 = sA[1];
          #pragma unroll
          for (int j = 0; j < 8; j++) {
            float seA = (j < 4) ? ((const float*)&sA0)[j] : ((const float*)&sA1)[j - 4];
            acc[j] += fmaxf(fmaf(bf2f((unsigned short)xA[j]), scl8[j], seA), 0.0f);
          }
          e += 4;
        }
        int rem = deg - e;  // 0..3
        if (grp < rem) {
          int pA = ep[e + grp];
          short8 xA = in8[(pA & 0xFFFF) * 16 + c8];
          const float4* sA = (const float4*)&sheL[((pA >> 16) << 7) + c8 * 8];
          float4 sA0 = sA[0], sA1 = sA[1];
          #pragma unroll
          for (int j = 0; j < 8; j++) {
            float seA = (j < 4) ? ((const float*)&sA0)[j] : ((const float*)&sA1)[j - 4];
            acc[j] += fmaxf(fmaf(bf2f((unsigned short)xA[j]), scl8[j], seA), 0.0f);
          }
        }
      }
      #pragma unroll
      for (int j = 0; j < 8; j++) {
        acc[j] += __shfl_xor(acc[j], 16);
        acc[j] += __shfl_xor(acc[j], 32);
      }
      if (grp == 0) {  // rows >= NT stay zero (pad rows)
        float4 lo = make_float4(acc[0], acc[1], acc[2], acc[3]);
        float4 hi = make_float4(acc[4], acc[5], acc[6], acc[7]);
        *(float4*)&hA[n * LDAF + c8 * 8] = lo;
        *(float4*)&hA[n * LDAF + c8 * 8 + 4] = hi;
      }
    }
  }
  __syncthreads();

  const int col = lane & 15;
  const int quad = lane >> 4;
  const int rbase = quad * 4;
  const int ch0 = wave * 16 + col;  // this wave's 16-channel tile
  const int aoff = quad * 8;

  // ---- phase 2: GEMM1 (hA @ W1 + b1, relu) -> back into hA ----
  {
    f32x4 a[4];
    #pragma unroll
    for (int rt = 0; rt < 4; rt++) a[rt] = (f32x4){0.f, 0.f, 0.f, 0.f};
    #pragma unroll
    for (int q = 0; q < 4; q++) {
      int f0 = wave * 256 + q * 64 + lane;
      short8 b0h = Wh[f0], b0l = Wl[f0];
      #pragma unroll
      for (int rt = 0; rt < 4; rt++) {
        short8 ah, al;
        split8(&hA[(rt * 16 + col) * LDAF + q * 32 + aoff], ah, al);
        a[rt] = __builtin_amdgcn_mfma_f32_16x16x32_bf16(ah, b0h, a[rt], 0, 0, 0);
        a[rt] = __builtin_amdgcn_mfma_f32_16x16x32_bf16(al, b0h, a[rt], 0, 0, 0);
        a[rt] = __builtin_amdgcn_mfma_f32_16x16x32_bf16(ah, b0l, a[rt], 0, 0, 0);
      }
    }
    __syncthreads();  // all GEMM1 reads of hA complete
    float bb = b1[ch0];
    #pragma unroll
    for (int rt = 0; rt < 4; rt++)
      #pragma unroll
      for (int r = 0; r < 4; r++)
        hA[(rt * 16 + rbase + r) * LDAF + ch0] = fmaxf(a[rt][r] + bb, 0.0f);
  }
  __syncthreads();

  // ---- phase 3: GEMM2 (h1 @ W2 + b2, relu) -> back into hA ----
  {
    f32x4 a[4];
    #pragma unroll
    for (int rt = 0; rt < 4; rt++) a[rt] = (f32x4){0.f, 0.f, 0.f, 0.f};
    #pragma unroll
    for (int q = 0; q < 4; q++) {
      int f0 = 2048 + wave * 256 + q * 64 + lane;  // gemm2 frags
      short8 b0h = Wh[f0], b0l = Wl[f0];
      #pragma unroll
      for (int rt = 0; rt < 4; rt++) {
        short8 ah, al;
        split8(&hA[(rt * 16 + col) * LDAF + q * 32 + aoff], ah, al);
        a[rt] = __builtin_amdgcn_mfma_f32_16x16x32_bf16(ah, b0h, a[rt], 0, 0, 0);
        a[rt] = __builtin_amdgcn_mfma_f32_16x16x32_bf16(al, b0h, a[rt], 0, 0, 0);
        a[rt] = __builtin_amdgcn_mfma_f32_16x16x32_bf16(ah, b0l, a[rt], 0, 0, 0);
      }
    }
    __syncthreads();  // all GEMM2 reads complete
    float bb = b2[ch0];
    #pragma unroll
    for (int rt = 0; rt < 4; rt++)
      #pragma unroll
      for (int r = 0; r < 4; r++)
        hA[(rt * 16 + rbase + r) * LDAF + ch0] = fmaxf(a[rt][r] + bb, 0.0f);
  }
  __syncthreads();

  // ---- phase 4: epilogue (h2 in hA); first 256 threads only ----
  if (tid < 256) {
    const int c = tid & 127;
    const int yy = tid >> 7;  // 0/1 -> rows [yy*25, yy*25+25)
    float lsum = 0.0f, lsq = 0.0f;
    if (out_bf) {
      #pragma unroll 5
      for (int i = 0; i < 25; i++) {
        int n = yy * 25 + i;
        float v = hA[n * LDAF + c];
        out_bf[(base + n) * HID + c] = f2bf(v);
        lsum += v;
        lsq += v * v;
      }
    } else {
      int curg = -1;
      float pacc = 0.0f;
      for (int i = 0; i < 25; i++) {
        int n = yy * 25 + i;
        float v = hA[n * LDAF + c];
        lsum += v;
        lsq += v * v;
        int bg = batch[base + n];
        if (bg != curg) {
          if (curg >= 0) unsafeAtomicAdd(&gpool[curg * HID + c], pacc);
          curg = bg;
          pacc = 0.0f;
        }
        pacc += v;
      }
      if (curg >= 0) unsafeAtomicAdd(&gpool[curg * HID + c], pacc);
    }
    unsafeAtomicAdd(&stats[c], lsum);
    unsafeAtomicAdd(&stats[HID + c], lsq);
  }
}

// ---------------------------------------------------------------------------
// out[g,c] = scl_c * gpool[g,c] + cnt_g * sh_c  (BN affine commutes with pool)
__device__ __forceinline__ int lbound(const int* __restrict__ arr, int n,
                                      int key) {
  int lo = 0, hi = n;
  while (lo < hi) {
    int mid = (lo + hi) >> 1;
    if (arr[mid] < key) lo = mid + 1; else hi = mid;
  }
  return lo;
}

__global__ __launch_bounds__(128) void finish_kernel(
    const float* __restrict__ gpool, const float* __restrict__ stats,
    const float* __restrict__ gam, const float* __restrict__ bet,
    const int* __restrict__ batch, float* __restrict__ out) {
  __shared__ int cnt_s;
  int g = blockIdx.x, c = threadIdx.x;
  if (c == 0)
    cnt_s = lbound(batch, NNODES, g + 1) - lbound(batch, NNODES, g);
  __syncthreads();
  float mu = stats[c] * (1.0f / NNODES);
  float var = stats[HID + c] * (1.0f / NNODES) - mu * mu;
  float scl = gam[c] * rsqrtf(var + BN_EPS);
  float sh = bet[c] - mu * scl;
  out[g * HID + c] = fmaf(gpool[g * HID + c], scl, (float)cnt_s * sh);
}

// ---------------------------------------------------------------------------
extern "C" void kernel_launch(void* const* d_in, const int* in_sizes, int n_in,
                              void* d_out, int out_size, void* d_ws, size_t ws_size,
                              hipStream_t stream) {
  const int* x_idx = (const int*)d_in[0];
  const int* eidx = (const int*)d_in[1];   // [2, E]: src row then dst row
  const int* eattr = (const int*)d_in[2];
  const int* batch = (const int*)d_in[3];
  const float* node_emb = (const float*)d_in[4];
  const float* edge_emb = (const float*)d_in[5];
  const float* W1 = (const float*)d_in[6];
  const float* b1 = (const float*)d_in[7];
  const float* W2 = (const float*)d_in[8];
  const float* b2 = (const float*)d_in[9];
  const float* bn_g = (const float*)d_in[10];
  const float* bn_b = (const float*)d_in[11];
  float* out = (float*)d_out;

  const size_t nfeat = (size_t)NNODES * HID;
  unsigned short* xbf = (unsigned short*)d_ws;  // [N,H] bf16
  unsigned short* h2bf = xbf + nfeat;           // [N,H] bf16
  float* stats0 = (float*)(h2bf + nfeat);       // [2,H]
  float* stats1 = stats0 + 2 * HID;             // [2,H]
  float* gpool = stats1 + 2 * HID;              // [G,H]
  int* cnt = (int*)(gpool + NGRAPHS * HID);     // [N]  (zeroed with stats)
  int* eout = cnt + NNODES;                     // [N*CAP]
  unsigned short* Wpk = (unsigned short*)(eout + (size_t)NNODES * CAP);
  size_t needed = (size_t)((char*)(Wpk + 131072) - (char*)d_ws);
  if (ws_size < needed) return;  // fails validation loudly, doesn't corrupt

  // zero stats0, stats1, gpool, cnt in one shot (contiguous)
  hipMemsetAsync(stats0, 0, (4 * HID + NGRAPHS * HID + NNODES) * sizeof(int),
                 stream);

  prep_kernel<<<1024, 256, 0, stream>>>(x_idx, node_emb, (unsigned int*)xbf,
                                        eidx, eattr, cnt, eout, W1, W2, Wpk);

  const short8* Wfh = (const short8*)Wpk;  // 8192 frags (hi)
  const short8* Wfl = Wfh + 8192;          // 8192 frags (lo)
  // layer 0: in = xbf (identity affine), out -> h2bf, stats0
  gine_mlp_kernel<<<GRID_GINE, 512, 0, stream>>>(
      xbf, nullptr, nullptr, nullptr, cnt, eout, edge_emb,
      Wfh + 0 * 2048, Wfl + 0 * 2048, b1, b2, h2bf, stats0, nullptr, nullptr);
  // layer 1: in = h2bf with BN(layer0) folded, out -> gpool + stats1
  gine_mlp_kernel<<<GRID_GINE, 512, 0, stream>>>(
      h2bf, stats0, bn_g, bn_b, cnt, eout, edge_emb,
      Wfh + 2 * 2048, Wfl + 2 * 2048, b1 + HID, b2 + HID, nullptr, stats1,
      batch, gpool);
  // final: out = scl*gpool + cnt*sh
  finish_kernel<<<NGRAPHS, 128, 0, stream>>>(gpool, stats1, bn_g + HID,
                                             bn_b + HID, batch, out);
}